// Round 7
// baseline (1121.797 us; speedup 1.0000x reference)
//
#include <hip/hip_runtime.h>
#include <hip/hip_bf16.h>
#include <math.h>

// RQ-VAE pipeline. Index path = numpy-fp32 bit-exact (validated r3-r6).
// Round 7: vq4 — half-codebook LDS staging (32KB -> 4 blocks/CU, 2x waves),
// compiler-pipelined pair scan, winner gathered from global (same bits).
// Encoder/decoder GEMMs get register double-buffering of global tiles.

#define N_ROWS 131072
#define D_IN   384
#define H_DIM  256
#define L_DIM  32
#define K_CB   512
#define Q_ST   4
#define VQ_ROWS 256
#define NPART  (N_ROWS / VQ_ROWS)   // 512 commit partials

typedef __attribute__((ext_vector_type(8))) short short8v;
typedef __attribute__((ext_vector_type(4))) float f32x4;

__device__ __forceinline__ ushort f2bf(float v)
{
    __hip_bfloat16 b = __float2bfloat16(v);
    return *reinterpret_cast<ushort*>(&b);
}

// np.sum(v*v) for n=32: numpy pairwise 8-accumulator order, products pre-rounded.
__device__ __forceinline__ float np_sumsq32(const float* __restrict__ v)
{
    #pragma clang fp contract(off)
    float s0 = v[0]*v[0], s1 = v[1]*v[1], s2 = v[2]*v[2], s3 = v[3]*v[3];
    float s4 = v[4]*v[4], s5 = v[5]*v[5], s6 = v[6]*v[6], s7 = v[7]*v[7];
    s0 = s0 + v[8]*v[8];   s1 = s1 + v[9]*v[9];   s2 = s2 + v[10]*v[10]; s3 = s3 + v[11]*v[11];
    s4 = s4 + v[12]*v[12]; s5 = s5 + v[13]*v[13]; s6 = s6 + v[14]*v[14]; s7 = s7 + v[15]*v[15];
    s0 = s0 + v[16]*v[16]; s1 = s1 + v[17]*v[17]; s2 = s2 + v[18]*v[18]; s3 = s3 + v[19]*v[19];
    s4 = s4 + v[20]*v[20]; s5 = s5 + v[21]*v[21]; s6 = s6 + v[22]*v[22]; s7 = s7 + v[23]*v[23];
    s0 = s0 + v[24]*v[24]; s1 = s1 + v[25]*v[25]; s2 = s2 + v[26]*v[26]; s3 = s3 + v[27]*v[27];
    s4 = s4 + v[28]*v[28]; s5 = s5 + v[29]*v[29]; s6 = s6 + v[30]*v[30]; s7 = s7 + v[31]*v[31];
    return ((s0 + s1) + (s2 + s3)) + ((s4 + s5) + (s6 + s7));
}

// ---------------- fp32 tiled GEMM (encoder; bit-exact path) -----------------------
// 128x128 tile, BK=32, 256 thr, 8x8/thread. Register double-buffer of the next
// global tile overlaps HBM latency with the FMA loop. FMA chains unchanged.
template<bool RELU>
__global__ __launch_bounds__(256)
void gemm_bias(const float* __restrict__ A, const float* __restrict__ B,
               const float* __restrict__ bias, float* __restrict__ C,
               int K, int Nout)
{
    #pragma clang fp contract(off)
    __shared__ float As2[32][132];   // [k][row]
    __shared__ float Bs[32][128];    // [k][col]
    const int t  = threadIdx.x;
    const int tc = t & 15;
    const int tr = t >> 4;
    const size_t row0 = (size_t)blockIdx.x * 128;
    const int    col0 = blockIdx.y * 128;

    float acc[8][8];
    #pragma unroll
    for (int i = 0; i < 8; ++i)
        #pragma unroll
        for (int j = 0; j < 8; ++j) acc[i][j] = 0.f;

    const int ar = t >> 3, ak = (t & 7) << 2;
    const int br = t >> 5, bc = (t & 31) << 2;

    float4 Arg[4], Brg[4];
    #pragma unroll
    for (int i = 0; i < 4; ++i) {
        Arg[i] = *reinterpret_cast<const float4*>(A + (row0 + ar + (i << 5)) * (size_t)K + ak);
        Brg[i] = *reinterpret_cast<const float4*>(B + (size_t)(br + (i << 3)) * Nout + col0 + bc);
    }

    for (int k0 = 0; k0 < K; k0 += 32) {
        #pragma unroll
        for (int i = 0; i < 4; ++i) {
            int r = ar + (i << 5);
            As2[ak + 0][r] = Arg[i].x; As2[ak + 1][r] = Arg[i].y;
            As2[ak + 2][r] = Arg[i].z; As2[ak + 3][r] = Arg[i].w;
            *reinterpret_cast<float4*>(&Bs[br + (i << 3)][bc]) = Brg[i];
        }
        __syncthreads();
        if (k0 + 32 < K) {
            #pragma unroll
            for (int i = 0; i < 4; ++i) {
                Arg[i] = *reinterpret_cast<const float4*>(A + (row0 + ar + (i << 5)) * (size_t)K + k0 + 32 + ak);
                Brg[i] = *reinterpret_cast<const float4*>(B + (size_t)(k0 + 32 + br + (i << 3)) * Nout + col0 + bc);
            }
        }
        #pragma unroll
        for (int k = 0; k < 32; ++k) {
            float a[8], b[8];
            *reinterpret_cast<float4*>(&a[0]) = *reinterpret_cast<const float4*>(&As2[k][tr << 3]);
            *reinterpret_cast<float4*>(&a[4]) = *reinterpret_cast<const float4*>(&As2[k][(tr << 3) + 4]);
            *reinterpret_cast<float4*>(&b[0]) = *reinterpret_cast<const float4*>(&Bs[k][tc << 2]);
            *reinterpret_cast<float4*>(&b[4]) = *reinterpret_cast<const float4*>(&Bs[k][(tc << 2) + 64]);
            #pragma unroll
            for (int i = 0; i < 8; ++i)
                #pragma unroll
                for (int j = 0; j < 8; ++j) acc[i][j] = fmaf(a[i], b[j], acc[i][j]);
        }
        __syncthreads();
    }

    #pragma unroll
    for (int i = 0; i < 8; ++i) {
        size_t r = row0 + (tr << 3) + i;
        int c1 = col0 + (tc << 2);
        int c2 = c1 + 64;
        float v1[4], v2[4];
        #pragma unroll
        for (int j = 0; j < 4; ++j) {
            float u1 = acc[i][j]     + bias[c1 + j];
            float u2 = acc[i][j + 4] + bias[c2 + j];
            if (RELU) { u1 = fmaxf(u1, 0.0f); u2 = fmaxf(u2, 0.0f); }
            v1[j] = u1; v2[j] = u2;
        }
        *reinterpret_cast<float4*>(C + r * Nout + c1) = *reinterpret_cast<float4*>(&v1[0]);
        *reinterpret_cast<float4*>(C + r * Nout + c2) = *reinterpret_cast<float4*>(&v2[0]);
    }
}

// ---------------- z-GEMM: Z[M,32] = A[M,256] @ W[256,32] + b (bit-exact) ----------
__global__ __launch_bounds__(256)
void gemm_z(const float* __restrict__ A, const float* __restrict__ W,
            const float* __restrict__ bv, float* __restrict__ Z)
{
    #pragma clang fp contract(off)
    __shared__ float As2[32][132];
    __shared__ float Ws[32][36];
    const int t = threadIdx.x;
    const int cgz = t & 7, rgz = t >> 3;
    const size_t row0 = (size_t)blockIdx.x * 128;

    float acc[4][4];
    #pragma unroll
    for (int i = 0; i < 4; ++i)
        #pragma unroll
        for (int j = 0; j < 4; ++j) acc[i][j] = 0.f;

    const int ar = t >> 3, ak = (t & 7) << 2;
    for (int k0 = 0; k0 < H_DIM; k0 += 32) {
        #pragma unroll
        for (int i = 0; i < 4; ++i) {
            int r = ar + (i << 5);
            float4 v = *reinterpret_cast<const float4*>(A + (row0 + r) * (size_t)H_DIM + k0 + ak);
            As2[ak + 0][r] = v.x; As2[ak + 1][r] = v.y;
            As2[ak + 2][r] = v.z; As2[ak + 3][r] = v.w;
        }
        {
            int kr = t >> 3, cc = (t & 7) << 2;
            float4 v = *reinterpret_cast<const float4*>(W + (size_t)(k0 + kr) * L_DIM + cc);
            *reinterpret_cast<float4*>(&Ws[kr][cc]) = v;
        }
        __syncthreads();
        #pragma unroll
        for (int k = 0; k < 32; ++k) {
            float a[4], w[4];
            *reinterpret_cast<float4*>(&a[0]) = *reinterpret_cast<const float4*>(&As2[k][rgz << 2]);
            *reinterpret_cast<float4*>(&w[0]) = *reinterpret_cast<const float4*>(&Ws[k][cgz << 2]);
            #pragma unroll
            for (int i = 0; i < 4; ++i)
                #pragma unroll
                for (int j = 0; j < 4; ++j) acc[i][j] = fmaf(a[i], w[j], acc[i][j]);
        }
        __syncthreads();
    }
    #pragma unroll
    for (int i = 0; i < 4; ++i) {
        size_t row = row0 + (rgz << 2) + i;
        float v[4];
        #pragma unroll
        for (int j = 0; j < 4; ++j) v[j] = acc[i][j] + bv[(cgz << 2) + j];
        *reinterpret_cast<float4*>(Z + row * L_DIM + (cgz << 2)) = *reinterpret_cast<float4*>(&v[0]);
    }
}

// ---------------- cnorm (numpy order) ---------------------------------------------
__global__ __launch_bounds__(256)
void cnorm_kernel(const float* __restrict__ cbs, float* __restrict__ cnorm)
{
    #pragma clang fp contract(off)
    int g = blockIdx.x * 256 + threadIdx.x;
    const float* c = cbs + (size_t)g * L_DIM;
    float cl[L_DIM];
    #pragma unroll
    for (int l = 0; l < L_DIM; ++l) cl[l] = c[l];
    cnorm[g] = np_sumsq32(cl);
}

// ---------------- dec-weight prep: fp32 [K][N] -> bf16 transposed [N][K] ----------
__global__ __launch_bounds__(256)
void prep_wt(const float* __restrict__ W, ushort* __restrict__ Wt, int K, int N)
{
    int g = blockIdx.x * 256 + threadIdx.x;
    if (g >= K * N) return;
    int n = g / K, k = g - n * K;
    Wt[g] = f2bf(W[(size_t)k * N + n]);
}

// ---------------- residual VQ v4 (bit-exact; half-codebook staging) ---------------
// 256 thr = 256 rows/block. Codebook staged in 2 halves of 256 codewords (32KB)
// -> 4 blocks/CU (vs 2) for latency hiding. (bd,bi) carried across halves in
// ascending col order with strict < == np.argmin first-min. Winner gathered
// from global (identical bits). Dot chains / rr / d-formula unchanged.
__global__ __launch_bounds__(256)
void vq4_kernel(const float* __restrict__ zbuf, const float* __restrict__ cbs,
                const float* __restrict__ cnorm_g, ushort* __restrict__ zqb,
                float* __restrict__ idxOut, double* __restrict__ commitPart,
                int rowBase)
{
    #pragma clang fp contract(off)
    __shared__ float  cbL[256 * L_DIM];   // 32 KB (half codebook)
    __shared__ float  cnL[K_CB];          // 2 KB
    __shared__ double sred[256];          // 2 KB

    const int t = threadIdx.x;
    const size_t lrow = (size_t)blockIdx.x * VQ_ROWS + t;
    const size_t grow = (size_t)rowBase + lrow;

    float r[L_DIM];
    {
        const float4* zp = reinterpret_cast<const float4*>(zbuf + lrow * L_DIM);
        #pragma unroll
        for (int j = 0; j < 8; ++j) {
            float4 v = zp[j];
            r[4*j+0]=v.x; r[4*j+1]=v.y; r[4*j+2]=v.z; r[4*j+3]=v.w;
        }
    }

    int bidx[Q_ST];
    double cAcc = 0.0;

    #pragma unroll 1
    for (int q = 0; q < Q_ST; ++q) {
        const float4* cbq = reinterpret_cast<const float4*>(cbs + (size_t)q * K_CB * L_DIM);

        float rr = np_sumsq32(r);
        float bd = __builtin_inff();
        int   bi = 0;

        #pragma unroll 1
        for (int half = 0; half < 2; ++half) {
            __syncthreads();   // prior reads of cbL/cnL done
            {
                const float4* src = cbq + (half << 11);
                float4* dst = reinterpret_cast<float4*>(cbL);
                #pragma unroll
                for (int i = 0; i < 8; ++i) dst[t + (i << 8)] = src[t + (i << 8)];
                if (half == 0) {
                    cnL[t]       = cnorm_g[q * K_CB + t];
                    cnL[t + 256] = cnorm_g[q * K_CB + t + 256];
                }
            }
            __syncthreads();

            const int cb0 = half << 8;
            #pragma unroll 2
            for (int c = 0; c < 256; c += 2) {
                const float4* w0 = reinterpret_cast<const float4*>(cbL + (c << 5));
                const float4* w1 = w0 + 8;
                float a0 = 0.f, a1 = 0.f;   // single sequential FMA chain per col
                #pragma unroll
                for (int j = 0; j < 8; ++j) {
                    float4 u = w0[j], v = w1[j];   // wave-uniform -> LDS broadcast
                    a0 = fmaf(r[4*j+0], u.x, a0);  a1 = fmaf(r[4*j+0], v.x, a1);
                    a0 = fmaf(r[4*j+1], u.y, a0);  a1 = fmaf(r[4*j+1], v.y, a1);
                    a0 = fmaf(r[4*j+2], u.z, a0);  a1 = fmaf(r[4*j+2], v.z, a1);
                    a0 = fmaf(r[4*j+3], u.w, a0);  a1 = fmaf(r[4*j+3], v.w, a1);
                }
                float d0 = (rr - 2.0f * a0) + cnL[cb0 + c];
                float d1 = (rr - 2.0f * a1) + cnL[cb0 + c + 1];
                if (d0 < bd) { bd = d0; bi = cb0 + c; }      // strict < = np first-min
                if (d1 < bd) { bd = d1; bi = cb0 + c + 1; }
            }
        }
        bidx[q] = bi;

        // winner gather from GLOBAL codebook (same bits as the staged copy)
        {
            const float4* pw = cbq + ((size_t)bi << 3);
            float cs = 0.f;
            #pragma unroll
            for (int j = 0; j < 8; ++j) {
                float4 v = pw[j];
                float df;
                df = v.x - r[4*j+0]; cs = fmaf(df, df, cs); r[4*j+0] = r[4*j+0] - v.x;
                df = v.y - r[4*j+1]; cs = fmaf(df, df, cs); r[4*j+1] = r[4*j+1] - v.y;
                df = v.z - r[4*j+2]; cs = fmaf(df, df, cs); r[4*j+2] = r[4*j+2] - v.z;
                df = v.w - r[4*j+3]; cs = fmaf(df, df, cs); r[4*j+3] = r[4*j+3] - v.w;
            }
            cAcc += (double)cs;
        }
    }

    {
        float4 iv = make_float4((float)bidx[0], (float)bidx[1], (float)bidx[2], (float)bidx[3]);
        *reinterpret_cast<float4*>(idxOut + grow * Q_ST) = iv;
    }

    // z_q = z - r_final (re-read z), stored bf16 for the MFMA decoder
    {
        const float4* zp = reinterpret_cast<const float4*>(zbuf + lrow * L_DIM);
        ushort zq16[L_DIM];
        #pragma unroll
        for (int j = 0; j < 8; ++j) {
            float4 v = zp[j];
            zq16[4*j+0] = f2bf(v.x - r[4*j+0]);
            zq16[4*j+1] = f2bf(v.y - r[4*j+1]);
            zq16[4*j+2] = f2bf(v.z - r[4*j+2]);
            zq16[4*j+3] = f2bf(v.w - r[4*j+3]);
        }
        uint4* o = reinterpret_cast<uint4*>(zqb + lrow * L_DIM);
        const uint4* s = reinterpret_cast<const uint4*>(zq16);
        #pragma unroll
        for (int j = 0; j < 4; ++j) o[j] = s[j];
    }

    sred[t] = cAcc;
    __syncthreads();
    for (int s = 128; s > 0; s >>= 1) {
        if (t < s) sred[t] += sred[t + s];
        __syncthreads();
    }
    if (t == 0) commitPart[rowBase / VQ_ROWS + blockIdx.x] = sred[0];
}

// ---------------- bf16 MFMA GEMM (decoder), reg double-buffered -------------------
template<bool RELU, bool OUTBF16>
__global__ __launch_bounds__(256)
void mfma_gemm(const ushort* __restrict__ A, const ushort* __restrict__ Bt,
               const float* __restrict__ bias, void* __restrict__ Cout,
               int K, int Nout)
{
    __shared__ ushort As[128][40];
    __shared__ ushort Bs[128][40];
    const int t    = threadIdx.x;
    const int lane = t & 63;
    const int wid  = t >> 6;
    const int wr = wid >> 1, wc = wid & 1;
    const size_t row0 = (size_t)blockIdx.x * 128;
    const int    col0 = blockIdx.y * 128;

    f32x4 acc[4][4] = {};
    const int srow = t >> 1;
    const int sh   = (t & 1) << 4;

    uint4 av0, av1, bv0, bv1;
    {
        const ushort* ap = A + (row0 + srow) * (size_t)K + sh;
        av0 = *reinterpret_cast<const uint4*>(ap);
        av1 = *reinterpret_cast<const uint4*>(ap + 8);
        const ushort* bp = Bt + (size_t)(col0 + srow) * K + sh;
        bv0 = *reinterpret_cast<const uint4*>(bp);
        bv1 = *reinterpret_cast<const uint4*>(bp + 8);
    }

    for (int k0 = 0; k0 < K; k0 += 32) {
        *reinterpret_cast<uint4*>(&As[srow][sh])     = av0;
        *reinterpret_cast<uint4*>(&As[srow][sh + 8]) = av1;
        *reinterpret_cast<uint4*>(&Bs[srow][sh])     = bv0;
        *reinterpret_cast<uint4*>(&Bs[srow][sh + 8]) = bv1;
        __syncthreads();
        if (k0 + 32 < K) {
            const ushort* ap = A + (row0 + srow) * (size_t)K + k0 + 32 + sh;
            av0 = *reinterpret_cast<const uint4*>(ap);
            av1 = *reinterpret_cast<const uint4*>(ap + 8);
            const ushort* bp = Bt + (size_t)(col0 + srow) * K + k0 + 32 + sh;
            bv0 = *reinterpret_cast<const uint4*>(bp);
            bv1 = *reinterpret_cast<const uint4*>(bp + 8);
        }
        const int l15 = lane & 15, lk = (lane >> 4) << 3;
        short8v af[4], bf[4];
        #pragma unroll
        for (int f = 0; f < 4; ++f) {
            af[f] = *reinterpret_cast<const short8v*>(&As[(wr << 6) + (f << 4) + l15][lk]);
            bf[f] = *reinterpret_cast<const short8v*>(&Bs[(wc << 6) + (f << 4) + l15][lk]);
        }
        #pragma unroll
        for (int i = 0; i < 4; ++i)
            #pragma unroll
            for (int j = 0; j < 4; ++j)
                acc[i][j] = __builtin_amdgcn_mfma_f32_16x16x32_bf16(af[i], bf[j], acc[i][j], 0, 0, 0);
        __syncthreads();
    }

    const int l15 = lane & 15, lr4 = (lane >> 4) << 2;
    #pragma unroll
    for (int i = 0; i < 4; ++i) {
        #pragma unroll
        for (int j = 0; j < 4; ++j) {
            int col = col0 + (wc << 6) + (j << 4) + l15;
            float bv = bias[col];
            #pragma unroll
            for (int rj = 0; rj < 4; ++rj) {
                size_t row = row0 + (wr << 6) + (i << 4) + lr4 + rj;
                float v = acc[i][j][rj] + bv;
                if (RELU) v = fmaxf(v, 0.f);
                if (OUTBF16)
                    reinterpret_cast<ushort*>(Cout)[row * Nout + col] = f2bf(v);
                else
                    reinterpret_cast<float*>(Cout)[row * Nout + col] = v;
            }
        }
    }
}

// ---------------- final commit reduction ------------------------------------------
__global__ __launch_bounds__(256)
void commit_finalize(const double* __restrict__ commitPart, float* __restrict__ outCommit)
{
    __shared__ double sred[256];
    const int t = threadIdx.x;
    double s = 0.0;
    for (int i = t; i < NPART; i += 256) s += commitPart[i];
    sred[t] = s;
    __syncthreads();
    for (int st = 128; st > 0; st >>= 1) {
        if (t < st) sred[t] += sred[t + st];
        __syncthreads();
    }
    if (t == 0)
        outCommit[0] = (float)(sred[0] / ((double)N_ROWS * (double)L_DIM));
}

extern "C" void kernel_launch(void* const* d_in, const int* in_sizes, int n_in,
                              void* d_out, int out_size, void* d_ws, size_t ws_size,
                              hipStream_t stream)
{
    const float* x      = (const float*)d_in[0];
    const float* enc_w1 = (const float*)d_in[1];
    const float* enc_b1 = (const float*)d_in[2];
    const float* enc_w2 = (const float*)d_in[3];
    const float* enc_b2 = (const float*)d_in[4];
    const float* enc_w3 = (const float*)d_in[5];
    const float* enc_b3 = (const float*)d_in[6];
    const float* dec_w1 = (const float*)d_in[7];
    const float* dec_b1 = (const float*)d_in[8];
    const float* dec_w2 = (const float*)d_in[9];
    const float* dec_b2 = (const float*)d_in[10];
    const float* dec_w3 = (const float*)d_in[11];
    const float* dec_b3 = (const float*)d_in[12];
    const float* cbs    = (const float*)d_in[13];

    float* out       = (float*)d_out;
    float* xrec      = out;
    float* idxOut    = out + (size_t)N_ROWS * D_IN;
    float* commitOut = idxOut + (size_t)N_ROWS * Q_ST;

    // ws layout:
    //   cnorm  f32[2048]   @0       | commit f64[512] @8192
    //   w1t u16[256*32]    @12288   | w2t u16[256*256] @28672 | w3t u16[384*256] @159744
    //   bufs @360448
    char*   wsb        = (char*)d_ws;
    float*  cnorm      = (float*)wsb;
    double* commitPart = (double*)(wsb + 8192);
    ushort* w1t        = (ushort*)(wsb + 12288);
    ushort* w2t        = (ushort*)(wsb + 28672);
    ushort* w3t        = (ushort*)(wsb + 159744);
    char*   bufs       = wsb + 360448;

    // per-row bytes: zbuf 128 + bufA 1024 + bufB 1024 + zqb 64 + h1b 512 + h2b 512 = 3264
    size_t availB = (ws_size > 360448) ? ws_size - 360448 : 0;
    long long chunk = (long long)(availB / 3264);
    chunk = (chunk / 256) * 256;
    if (chunk > N_ROWS) chunk = N_ROWS;
    if (chunk < 256) chunk = 256;

    float*  zbuf = (float*)bufs;
    float*  bufA = zbuf + (size_t)chunk * L_DIM;
    float*  bufB = bufA + (size_t)chunk * H_DIM;
    ushort* zqb  = (ushort*)(bufB + (size_t)chunk * H_DIM);
    ushort* h1b  = zqb + (size_t)chunk * L_DIM;
    ushort* h2b  = h1b + (size_t)chunk * H_DIM;

    cnorm_kernel<<<8, 256, 0, stream>>>(cbs, cnorm);
    prep_wt<<<(L_DIM  * H_DIM + 255) / 256, 256, 0, stream>>>(dec_w1, w1t, L_DIM, H_DIM);
    prep_wt<<<(H_DIM * H_DIM + 255) / 256, 256, 0, stream>>>(dec_w2, w2t, H_DIM, H_DIM);
    prep_wt<<<(H_DIM * D_IN + 255) / 256, 256, 0, stream>>>(dec_w3, w3t, H_DIM, D_IN);

    for (long long ro = 0; ro < N_ROWS; ro += chunk) {
        long long R = N_ROWS - ro;
        if (R > chunk) R = chunk;
        dim3 g2((unsigned)(R / 128), 2);
        dim3 g3((unsigned)(R / 128), 3);
        // encoder (bit-exact fp32)
        gemm_bias<true><<<g2, 256, 0, stream>>>(x + ro * D_IN, enc_w1, enc_b1, bufA, D_IN, H_DIM);
        gemm_bias<true><<<g2, 256, 0, stream>>>(bufA, enc_w2, enc_b2, bufB, H_DIM, H_DIM);
        gemm_z<<<(unsigned)(R / 128), 256, 0, stream>>>(bufB, enc_w3, enc_b3, zbuf);
        // residual VQ (bit-exact; writes bf16 z_q)
        vq4_kernel<<<(unsigned)(R / VQ_ROWS), 256, 0, stream>>>(zbuf, cbs, cnorm, zqb,
                                                                idxOut, commitPart, (int)ro);
        // decoder (bf16 MFMA)
        mfma_gemm<true,  true ><<<g2, 256, 0, stream>>>(zqb, w1t, dec_b1, h1b, L_DIM, H_DIM);
        mfma_gemm<true,  true ><<<g2, 256, 0, stream>>>(h1b, w2t, dec_b2, h2b, H_DIM, H_DIM);
        mfma_gemm<false, false><<<g3, 256, 0, stream>>>(h2b, w3t, dec_b3, xrec + ro * D_IN, H_DIM, D_IN);
    }

    commit_finalize<<<1, 256, 0, stream>>>(commitPart, commitOut);
}

// Round 8
// 1017.245 us; speedup vs baseline: 1.1028x; 1.1028x over previous
//
#include <hip/hip_runtime.h>
#include <hip/hip_bf16.h>
#include <math.h>

// RQ-VAE pipeline. Index path = numpy-fp32 bit-exact (validated r3-r6).
// Round 8: revert r7 regressions (GEMMs back to r6 form; vq back to full-64KB
// broadcast scan) + vq5: manual ping-pong register pipeline in the codeword
// scan so next pair's LDS reads are in flight during current pair's FMA chain.
// fmaf(-2,a,rr) fold is bit-identical to (rr-2*a) since 2*a is exact.

#define N_ROWS 131072
#define D_IN   384
#define H_DIM  256
#define L_DIM  32
#define K_CB   512
#define Q_ST   4
#define VQ_ROWS 256
#define NPART  (N_ROWS / VQ_ROWS)   // 512 commit partials

typedef __attribute__((ext_vector_type(8))) short short8v;
typedef __attribute__((ext_vector_type(4))) float f32x4;

__device__ __forceinline__ ushort f2bf(float v)
{
    __hip_bfloat16 b = __float2bfloat16(v);
    return *reinterpret_cast<ushort*>(&b);
}

// np.sum(v*v) for n=32: numpy pairwise 8-accumulator order, products pre-rounded.
__device__ __forceinline__ float np_sumsq32(const float* __restrict__ v)
{
    #pragma clang fp contract(off)
    float s0 = v[0]*v[0], s1 = v[1]*v[1], s2 = v[2]*v[2], s3 = v[3]*v[3];
    float s4 = v[4]*v[4], s5 = v[5]*v[5], s6 = v[6]*v[6], s7 = v[7]*v[7];
    s0 = s0 + v[8]*v[8];   s1 = s1 + v[9]*v[9];   s2 = s2 + v[10]*v[10]; s3 = s3 + v[11]*v[11];
    s4 = s4 + v[12]*v[12]; s5 = s5 + v[13]*v[13]; s6 = s6 + v[14]*v[14]; s7 = s7 + v[15]*v[15];
    s0 = s0 + v[16]*v[16]; s1 = s1 + v[17]*v[17]; s2 = s2 + v[18]*v[18]; s3 = s3 + v[19]*v[19];
    s4 = s4 + v[20]*v[20]; s5 = s5 + v[21]*v[21]; s6 = s6 + v[22]*v[22]; s7 = s7 + v[23]*v[23];
    s0 = s0 + v[24]*v[24]; s1 = s1 + v[25]*v[25]; s2 = s2 + v[26]*v[26]; s3 = s3 + v[27]*v[27];
    s4 = s4 + v[28]*v[28]; s5 = s5 + v[29]*v[29]; s6 = s6 + v[30]*v[30]; s7 = s7 + v[31]*v[31];
    return ((s0 + s1) + (s2 + s3)) + ((s4 + s5) + (s6 + s7));
}

// ---------------- fp32 tiled GEMM (encoder; bit-exact path; r6 version) -----------
template<bool RELU>
__global__ __launch_bounds__(256)
void gemm_bias(const float* __restrict__ A, const float* __restrict__ B,
               const float* __restrict__ bias, float* __restrict__ C,
               int K, int Nout)
{
    #pragma clang fp contract(off)
    __shared__ float As2[32][132];   // [k][row]
    __shared__ float Bs[32][128];    // [k][col]
    const int t  = threadIdx.x;
    const int tc = t & 15;
    const int tr = t >> 4;
    const size_t row0 = (size_t)blockIdx.x * 128;
    const int    col0 = blockIdx.y * 128;

    float acc[8][8];
    #pragma unroll
    for (int i = 0; i < 8; ++i)
        #pragma unroll
        for (int j = 0; j < 8; ++j) acc[i][j] = 0.f;

    const int ar = t >> 3, ak = (t & 7) << 2;
    const int br = t >> 5, bc = (t & 31) << 2;

    for (int k0 = 0; k0 < K; k0 += 32) {
        #pragma unroll
        for (int i = 0; i < 4; ++i) {
            int r = ar + (i << 5);
            float4 v = *reinterpret_cast<const float4*>(A + (row0 + r) * (size_t)K + k0 + ak);
            As2[ak + 0][r] = v.x; As2[ak + 1][r] = v.y;
            As2[ak + 2][r] = v.z; As2[ak + 3][r] = v.w;
        }
        #pragma unroll
        for (int i = 0; i < 4; ++i) {
            int r = br + (i << 3);
            float4 v = *reinterpret_cast<const float4*>(B + (size_t)(k0 + r) * Nout + col0 + bc);
            *reinterpret_cast<float4*>(&Bs[r][bc]) = v;
        }
        __syncthreads();
        #pragma unroll
        for (int k = 0; k < 32; ++k) {
            float a[8], b[8];
            *reinterpret_cast<float4*>(&a[0]) = *reinterpret_cast<const float4*>(&As2[k][tr << 3]);
            *reinterpret_cast<float4*>(&a[4]) = *reinterpret_cast<const float4*>(&As2[k][(tr << 3) + 4]);
            *reinterpret_cast<float4*>(&b[0]) = *reinterpret_cast<const float4*>(&Bs[k][tc << 2]);
            *reinterpret_cast<float4*>(&b[4]) = *reinterpret_cast<const float4*>(&Bs[k][(tc << 2) + 64]);
            #pragma unroll
            for (int i = 0; i < 8; ++i)
                #pragma unroll
                for (int j = 0; j < 8; ++j) acc[i][j] = fmaf(a[i], b[j], acc[i][j]);
        }
        __syncthreads();
    }

    #pragma unroll
    for (int i = 0; i < 8; ++i) {
        size_t r = row0 + (tr << 3) + i;
        int c1 = col0 + (tc << 2);
        int c2 = c1 + 64;
        float v1[4], v2[4];
        #pragma unroll
        for (int j = 0; j < 4; ++j) {
            float u1 = acc[i][j]     + bias[c1 + j];
            float u2 = acc[i][j + 4] + bias[c2 + j];
            if (RELU) { u1 = fmaxf(u1, 0.0f); u2 = fmaxf(u2, 0.0f); }
            v1[j] = u1; v2[j] = u2;
        }
        *reinterpret_cast<float4*>(C + r * Nout + c1) = *reinterpret_cast<float4*>(&v1[0]);
        *reinterpret_cast<float4*>(C + r * Nout + c2) = *reinterpret_cast<float4*>(&v2[0]);
    }
}

// ---------------- z-GEMM: Z[M,32] = A[M,256] @ W[256,32] + b (bit-exact) ----------
__global__ __launch_bounds__(256)
void gemm_z(const float* __restrict__ A, const float* __restrict__ W,
            const float* __restrict__ bv, float* __restrict__ Z)
{
    #pragma clang fp contract(off)
    __shared__ float As2[32][132];
    __shared__ float Ws[32][36];
    const int t = threadIdx.x;
    const int cgz = t & 7, rgz = t >> 3;
    const size_t row0 = (size_t)blockIdx.x * 128;

    float acc[4][4];
    #pragma unroll
    for (int i = 0; i < 4; ++i)
        #pragma unroll
        for (int j = 0; j < 4; ++j) acc[i][j] = 0.f;

    const int ar = t >> 3, ak = (t & 7) << 2;
    for (int k0 = 0; k0 < H_DIM; k0 += 32) {
        #pragma unroll
        for (int i = 0; i < 4; ++i) {
            int r = ar + (i << 5);
            float4 v = *reinterpret_cast<const float4*>(A + (row0 + r) * (size_t)H_DIM + k0 + ak);
            As2[ak + 0][r] = v.x; As2[ak + 1][r] = v.y;
            As2[ak + 2][r] = v.z; As2[ak + 3][r] = v.w;
        }
        {
            int kr = t >> 3, cc = (t & 7) << 2;
            float4 v = *reinterpret_cast<const float4*>(W + (size_t)(k0 + kr) * L_DIM + cc);
            *reinterpret_cast<float4*>(&Ws[kr][cc]) = v;
        }
        __syncthreads();
        #pragma unroll
        for (int k = 0; k < 32; ++k) {
            float a[4], w[4];
            *reinterpret_cast<float4*>(&a[0]) = *reinterpret_cast<const float4*>(&As2[k][rgz << 2]);
            *reinterpret_cast<float4*>(&w[0]) = *reinterpret_cast<const float4*>(&Ws[k][cgz << 2]);
            #pragma unroll
            for (int i = 0; i < 4; ++i)
                #pragma unroll
                for (int j = 0; j < 4; ++j) acc[i][j] = fmaf(a[i], w[j], acc[i][j]);
        }
        __syncthreads();
    }
    #pragma unroll
    for (int i = 0; i < 4; ++i) {
        size_t row = row0 + (rgz << 2) + i;
        float v[4];
        #pragma unroll
        for (int j = 0; j < 4; ++j) v[j] = acc[i][j] + bv[(cgz << 2) + j];
        *reinterpret_cast<float4*>(Z + row * L_DIM + (cgz << 2)) = *reinterpret_cast<float4*>(&v[0]);
    }
}

// ---------------- cnorm (numpy order) ---------------------------------------------
__global__ __launch_bounds__(256)
void cnorm_kernel(const float* __restrict__ cbs, float* __restrict__ cnorm)
{
    #pragma clang fp contract(off)
    int g = blockIdx.x * 256 + threadIdx.x;
    const float* c = cbs + (size_t)g * L_DIM;
    float cl[L_DIM];
    #pragma unroll
    for (int l = 0; l < L_DIM; ++l) cl[l] = c[l];
    cnorm[g] = np_sumsq32(cl);
}

// ---------------- dec-weight prep: fp32 [K][N] -> bf16 transposed [N][K] ----------
__global__ __launch_bounds__(256)
void prep_wt(const float* __restrict__ W, ushort* __restrict__ Wt, int K, int N)
{
    int g = blockIdx.x * 256 + threadIdx.x;
    if (g >= K * N) return;
    int n = g / K, k = g - n * K;
    Wt[g] = f2bf(W[(size_t)k * N + n]);
}

// ---------------- residual VQ v5: broadcast scan + ping-pong pipeline -------------
// 256 thr = 256 rows/block, 1 row/lane, full 64KB codebook staged per stage.
// c-loop processes 4 cols/iter in two ping-pong register sets: while pair A
// (c,c+1) is in the FMA chain, pair B (c+2,c+3) ds_reads are in flight.
// Evaluation stays ascending with strict <  == np.argmin first-min.
// d = fmaf(-2,a,rr) + cn  is bit-identical to (rr - 2*a) + cn (2*a exact).
__global__ __launch_bounds__(256, 2)
void vq5_kernel(const float* __restrict__ zbuf, const float* __restrict__ cbs,
                const float* __restrict__ cnorm_g, ushort* __restrict__ zqb,
                float* __restrict__ idxOut, double* __restrict__ commitPart,
                int rowBase)
{
    #pragma clang fp contract(off)
    __shared__ float  cbL[K_CB * L_DIM];   // 64 KB
    __shared__ float  cnL[K_CB];           // 2 KB
    __shared__ double sred[256];           // 2 KB

    const int t = threadIdx.x;
    const size_t lrow = (size_t)blockIdx.x * VQ_ROWS + t;
    const size_t grow = (size_t)rowBase + lrow;

    float r[L_DIM];
    {
        const float4* zp = reinterpret_cast<const float4*>(zbuf + lrow * L_DIM);
        #pragma unroll
        for (int j = 0; j < 8; ++j) {
            float4 v = zp[j];
            r[4*j+0]=v.x; r[4*j+1]=v.y; r[4*j+2]=v.z; r[4*j+3]=v.w;
        }
    }

    int bidx[Q_ST];
    double cAcc = 0.0;

    #pragma unroll 1
    for (int q = 0; q < Q_ST; ++q) {
        __syncthreads();   // prior stage's cbL reads done before overwrite
        {
            const float4* src = reinterpret_cast<const float4*>(cbs + (size_t)q * K_CB * L_DIM);
            float4* dst = reinterpret_cast<float4*>(cbL);
            #pragma unroll
            for (int i = 0; i < 16; ++i) dst[t + (i << 8)] = src[t + (i << 8)];
            cnL[t]       = cnorm_g[q * K_CB + t];
            cnL[t + 256] = cnorm_g[q * K_CB + t + 256];
        }
        __syncthreads();

        float rr = np_sumsq32(r);
        float bd = __builtin_inff();
        int   bi = 0;

        // prime pipeline: pair A = cols 0,1
        float4 A0[8], A1[8], B0[8], B1[8];
        {
            const float4* w0 = reinterpret_cast<const float4*>(cbL);
            #pragma unroll
            for (int j = 0; j < 8; ++j) { A0[j] = w0[j]; A1[j] = w0[8 + j]; }
        }

        #pragma unroll 1
        for (int c = 0; c < K_CB; c += 4) {
            // issue loads for pair B = cols c+2,c+3 (always in range: K_CB%4==0)
            {
                const float4* wb = reinterpret_cast<const float4*>(cbL + ((c + 2) << 5));
                #pragma unroll
                for (int j = 0; j < 8; ++j) { B0[j] = wb[j]; B1[j] = wb[8 + j]; }
            }
            // compute pair A = cols c, c+1
            {
                float a0 = 0.f, a1 = 0.f;
                #pragma unroll
                for (int j = 0; j < 8; ++j) {
                    float4 u = A0[j], v = A1[j];
                    a0 = fmaf(r[4*j+0], u.x, a0);  a1 = fmaf(r[4*j+0], v.x, a1);
                    a0 = fmaf(r[4*j+1], u.y, a0);  a1 = fmaf(r[4*j+1], v.y, a1);
                    a0 = fmaf(r[4*j+2], u.z, a0);  a1 = fmaf(r[4*j+2], v.z, a1);
                    a0 = fmaf(r[4*j+3], u.w, a0);  a1 = fmaf(r[4*j+3], v.w, a1);
                }
                float d0 = fmaf(-2.0f, a0, rr) + cnL[c];
                float d1 = fmaf(-2.0f, a1, rr) + cnL[c + 1];
                if (d0 < bd) { bd = d0; bi = c; }
                if (d1 < bd) { bd = d1; bi = c + 1; }
            }
            // issue loads for next pair A = cols c+4,c+5
            if (c + 4 < K_CB) {
                const float4* wa = reinterpret_cast<const float4*>(cbL + ((c + 4) << 5));
                #pragma unroll
                for (int j = 0; j < 8; ++j) { A0[j] = wa[j]; A1[j] = wa[8 + j]; }
            }
            // compute pair B = cols c+2, c+3
            {
                float a0 = 0.f, a1 = 0.f;
                #pragma unroll
                for (int j = 0; j < 8; ++j) {
                    float4 u = B0[j], v = B1[j];
                    a0 = fmaf(r[4*j+0], u.x, a0);  a1 = fmaf(r[4*j+0], v.x, a1);
                    a0 = fmaf(r[4*j+1], u.y, a0);  a1 = fmaf(r[4*j+1], v.y, a1);
                    a0 = fmaf(r[4*j+2], u.z, a0);  a1 = fmaf(r[4*j+2], v.z, a1);
                    a0 = fmaf(r[4*j+3], u.w, a0);  a1 = fmaf(r[4*j+3], v.w, a1);
                }
                float d0 = fmaf(-2.0f, a0, rr) + cnL[c + 2];
                float d1 = fmaf(-2.0f, a1, rr) + cnL[c + 3];
                if (d0 < bd) { bd = d0; bi = c + 2; }
                if (d1 < bd) { bd = d1; bi = c + 3; }
            }
        }
        bidx[q] = bi;

        // winner gather from LDS (resident); residual + commit update (np order)
        {
            const float4* pw = reinterpret_cast<const float4*>(cbL + (bi << 5));
            float cs = 0.f;
            #pragma unroll
            for (int j = 0; j < 8; ++j) {
                float4 v = pw[j];
                float df;
                df = v.x - r[4*j+0]; cs = fmaf(df, df, cs); r[4*j+0] = r[4*j+0] - v.x;
                df = v.y - r[4*j+1]; cs = fmaf(df, df, cs); r[4*j+1] = r[4*j+1] - v.y;
                df = v.z - r[4*j+2]; cs = fmaf(df, df, cs); r[4*j+2] = r[4*j+2] - v.z;
                df = v.w - r[4*j+3]; cs = fmaf(df, df, cs); r[4*j+3] = r[4*j+3] - v.w;
            }
            cAcc += (double)cs;
        }
    }

    {
        float4 iv = make_float4((float)bidx[0], (float)bidx[1], (float)bidx[2], (float)bidx[3]);
        *reinterpret_cast<float4*>(idxOut + grow * Q_ST) = iv;
    }

    // z_q = z - r_final (re-read z), stored bf16 for the MFMA decoder
    {
        const float4* zp = reinterpret_cast<const float4*>(zbuf + lrow * L_DIM);
        ushort zq16[L_DIM];
        #pragma unroll
        for (int j = 0; j < 8; ++j) {
            float4 v = zp[j];
            zq16[4*j+0] = f2bf(v.x - r[4*j+0]);
            zq16[4*j+1] = f2bf(v.y - r[4*j+1]);
            zq16[4*j+2] = f2bf(v.z - r[4*j+2]);
            zq16[4*j+3] = f2bf(v.w - r[4*j+3]);
        }
        uint4* o = reinterpret_cast<uint4*>(zqb + lrow * L_DIM);
        const uint4* s = reinterpret_cast<const uint4*>(zq16);
        #pragma unroll
        for (int j = 0; j < 4; ++j) o[j] = s[j];
    }

    sred[t] = cAcc;
    __syncthreads();
    for (int s = 128; s > 0; s >>= 1) {
        if (t < s) sred[t] += sred[t + s];
        __syncthreads();
    }
    if (t == 0) commitPart[rowBase / VQ_ROWS + blockIdx.x] = sred[0];
}

// ---------------- bf16 MFMA GEMM (decoder; r6 version) ----------------------------
template<bool RELU, bool OUTBF16>
__global__ __launch_bounds__(256)
void mfma_gemm(const ushort* __restrict__ A, const ushort* __restrict__ Bt,
               const float* __restrict__ bias, void* __restrict__ Cout,
               int K, int Nout)
{
    __shared__ ushort As[128][40];
    __shared__ ushort Bs[128][40];
    const int t    = threadIdx.x;
    const int lane = t & 63;
    const int wid  = t >> 6;
    const int wr = wid >> 1, wc = wid & 1;
    const size_t row0 = (size_t)blockIdx.x * 128;
    const int    col0 = blockIdx.y * 128;

    f32x4 acc[4][4] = {};
    const int srow = t >> 1;
    const int sh   = (t & 1) << 4;

    for (int k0 = 0; k0 < K; k0 += 32) {
        {
            const ushort* ap = A + (row0 + srow) * (size_t)K + k0 + sh;
            uint4 v0 = *reinterpret_cast<const uint4*>(ap);
            uint4 v1 = *reinterpret_cast<const uint4*>(ap + 8);
            *reinterpret_cast<uint4*>(&As[srow][sh])     = v0;
            *reinterpret_cast<uint4*>(&As[srow][sh + 8]) = v1;
            const ushort* bp = Bt + (size_t)(col0 + srow) * K + k0 + sh;
            uint4 w0 = *reinterpret_cast<const uint4*>(bp);
            uint4 w1 = *reinterpret_cast<const uint4*>(bp + 8);
            *reinterpret_cast<uint4*>(&Bs[srow][sh])     = w0;
            *reinterpret_cast<uint4*>(&Bs[srow][sh + 8]) = w1;
        }
        __syncthreads();
        const int l15 = lane & 15, lk = (lane >> 4) << 3;
        short8v af[4], bf[4];
        #pragma unroll
        for (int f = 0; f < 4; ++f) {
            af[f] = *reinterpret_cast<const short8v*>(&As[(wr << 6) + (f << 4) + l15][lk]);
            bf[f] = *reinterpret_cast<const short8v*>(&Bs[(wc << 6) + (f << 4) + l15][lk]);
        }
        #pragma unroll
        for (int i = 0; i < 4; ++i)
            #pragma unroll
            for (int j = 0; j < 4; ++j)
                acc[i][j] = __builtin_amdgcn_mfma_f32_16x16x32_bf16(af[i], bf[j], acc[i][j], 0, 0, 0);
        __syncthreads();
    }

    const int l15 = lane & 15, lr4 = (lane >> 4) << 2;
    #pragma unroll
    for (int i = 0; i < 4; ++i) {
        #pragma unroll
        for (int j = 0; j < 4; ++j) {
            int col = col0 + (wc << 6) + (j << 4) + l15;
            float bv = bias[col];
            #pragma unroll
            for (int rj = 0; rj < 4; ++rj) {
                size_t row = row0 + (wr << 6) + (i << 4) + lr4 + rj;
                float v = acc[i][j][rj] + bv;
                if (RELU) v = fmaxf(v, 0.f);
                if (OUTBF16)
                    reinterpret_cast<ushort*>(Cout)[row * Nout + col] = f2bf(v);
                else
                    reinterpret_cast<float*>(Cout)[row * Nout + col] = v;
            }
        }
    }
}

// ---------------- final commit reduction ------------------------------------------
__global__ __launch_bounds__(256)
void commit_finalize(const double* __restrict__ commitPart, float* __restrict__ outCommit)
{
    __shared__ double sred[256];
    const int t = threadIdx.x;
    double s = 0.0;
    for (int i = t; i < NPART; i += 256) s += commitPart[i];
    sred[t] = s;
    __syncthreads();
    for (int st = 128; st > 0; st >>= 1) {
        if (t < st) sred[t] += sred[t + st];
        __syncthreads();
    }
    if (t == 0)
        outCommit[0] = (float)(sred[0] / ((double)N_ROWS * (double)L_DIM));
}

extern "C" void kernel_launch(void* const* d_in, const int* in_sizes, int n_in,
                              void* d_out, int out_size, void* d_ws, size_t ws_size,
                              hipStream_t stream)
{
    const float* x      = (const float*)d_in[0];
    const float* enc_w1 = (const float*)d_in[1];
    const float* enc_b1 = (const float*)d_in[2];
    const float* enc_w2 = (const float*)d_in[3];
    const float* enc_b2 = (const float*)d_in[4];
    const float* enc_w3 = (const float*)d_in[5];
    const float* enc_b3 = (const float*)d_in[6];
    const float* dec_w1 = (const float*)d_in[7];
    const float* dec_b1 = (const float*)d_in[8];
    const float* dec_w2 = (const float*)d_in[9];
    const float* dec_b2 = (const float*)d_in[10];
    const float* dec_w3 = (const float*)d_in[11];
    const float* dec_b3 = (const float*)d_in[12];
    const float* cbs    = (const float*)d_in[13];

    float* out       = (float*)d_out;
    float* xrec      = out;
    float* idxOut    = out + (size_t)N_ROWS * D_IN;
    float* commitOut = idxOut + (size_t)N_ROWS * Q_ST;

    // ws layout:
    //   cnorm  f32[2048]   @0       | commit f64[512] @8192
    //   w1t u16[256*32]    @12288   | w2t u16[256*256] @28672 | w3t u16[384*256] @159744
    //   bufs @360448
    char*   wsb        = (char*)d_ws;
    float*  cnorm      = (float*)wsb;
    double* commitPart = (double*)(wsb + 8192);
    ushort* w1t        = (ushort*)(wsb + 12288);
    ushort* w2t        = (ushort*)(wsb + 28672);
    ushort* w3t        = (ushort*)(wsb + 159744);
    char*   bufs       = wsb + 360448;

    // per-row bytes: zbuf 128 + bufA 1024 + bufB 1024 + zqb 64 + h1b 512 + h2b 512 = 3264
    size_t availB = (ws_size > 360448) ? ws_size - 360448 : 0;
    long long chunk = (long long)(availB / 3264);
    chunk = (chunk / 256) * 256;
    if (chunk > N_ROWS) chunk = N_ROWS;
    if (chunk < 256) chunk = 256;

    float*  zbuf = (float*)bufs;
    float*  bufA = zbuf + (size_t)chunk * L_DIM;
    float*  bufB = bufA + (size_t)chunk * H_DIM;
    ushort* zqb  = (ushort*)(bufB + (size_t)chunk * H_DIM);
    ushort* h1b  = zqb + (size_t)chunk * L_DIM;
    ushort* h2b  = h1b + (size_t)chunk * H_DIM;

    cnorm_kernel<<<8, 256, 0, stream>>>(cbs, cnorm);
    prep_wt<<<(L_DIM  * H_DIM + 255) / 256, 256, 0, stream>>>(dec_w1, w1t, L_DIM, H_DIM);
    prep_wt<<<(H_DIM * H_DIM + 255) / 256, 256, 0, stream>>>(dec_w2, w2t, H_DIM, H_DIM);
    prep_wt<<<(H_DIM * D_IN + 255) / 256, 256, 0, stream>>>(dec_w3, w3t, H_DIM, D_IN);

    for (long long ro = 0; ro < N_ROWS; ro += chunk) {
        long long R = N_ROWS - ro;
        if (R > chunk) R = chunk;
        dim3 g2((unsigned)(R / 128), 2);
        dim3 g3((unsigned)(R / 128), 3);
        // encoder (bit-exact fp32)
        gemm_bias<true><<<g2, 256, 0, stream>>>(x + ro * D_IN, enc_w1, enc_b1, bufA, D_IN, H_DIM);
        gemm_bias<true><<<g2, 256, 0, stream>>>(bufA, enc_w2, enc_b2, bufB, H_DIM, H_DIM);
        gemm_z<<<(unsigned)(R / 128), 256, 0, stream>>>(bufB, enc_w3, enc_b3, zbuf);
        // residual VQ (bit-exact; writes bf16 z_q)
        vq5_kernel<<<(unsigned)(R / VQ_ROWS), 256, 0, stream>>>(zbuf, cbs, cnorm, zqb,
                                                                idxOut, commitPart, (int)ro);
        // decoder (bf16 MFMA)
        mfma_gemm<true,  true ><<<g2, 256, 0, stream>>>(zqb, w1t, dec_b1, h1b, L_DIM, H_DIM);
        mfma_gemm<true,  true ><<<g2, 256, 0, stream>>>(h1b, w2t, dec_b2, h2b, H_DIM, H_DIM);
        mfma_gemm<false, false><<<g3, 256, 0, stream>>>(h2b, w3t, dec_b3, xrec + ro * D_IN, H_DIM, D_IN);
    }

    commit_finalize<<<1, 256, 0, stream>>>(commitPart, commitOut);
}